// Round 15
// baseline (26.578 us; speedup 1.0000x reference)
//
#include <hip/hip_runtime.h>
#include <hip/hip_fp16.h>
#include <cmath>

#define WS 11

typedef unsigned int u32x4_t __attribute__((ext_vector_type(4)));

struct GaussHalf {
    unsigned gA[WS];    // (g/sqrt2, g/sqrt2) as half2 bits — linear chain
    unsigned gS[WS];    // (g/2, g/2)         as half2 bits — square chain
    unsigned c11, c22;  // (C1,C1), (C2,C2)   as half2 bits
};

// ---- raw buffer loads vs a per-row SRD (num_records = 2048 bytes).
// OOB voffsets (negative-as-unsigned or >= 2048) return 0 in hardware —
// this IS the reference's W zero-padding, for free (R9-proven, absmax 0).
// NOTE: the SRD must be SGPR-resident: derive it from a readfirstlane'd
// row id (R14's compile failure was a VGPR-resident SRD).
__device__ __forceinline__ u32x4_t make_row_srsrc(const float* p) {
    const unsigned long long a = (unsigned long long)p;
    u32x4_t r;
    r.x = (unsigned)a;
    r.y = (unsigned)(a >> 32);
    r.z = 2048u;          // num_records (bytes, stride==0)
    r.w = 0x00020000u;    // raw untyped dword access
    return r;
}
__device__ __forceinline__ float4 bl_x4(u32x4_t srd, int voff) {
    float4 d;
    asm volatile("buffer_load_dwordx4 %0, %1, %2, 0 offen"
                 : "=v"(d) : "v"(voff), "s"(srd));
    return d;
}
__device__ __forceinline__ float bl_x1(u32x4_t srd, int voff) {
    float d;
    asm volatile("buffer_load_dword %0, %1, %2, 0 offen"
                 : "=v"(d) : "v"(voff), "s"(srd));
    return d;
}

// 16*3*512 = 24576 rows of 512 floats. ONE wave per row, 8 px/lane,
// 128-thread blocks (2 waves) for fine residency packing (best measured
// occupancy, R2, was the only 128-thread config). No LDS, no shuffles,
// no masks: halos via overlapping SRD loads with HW OOB-zero. f16 packed
// conv/epilogue (R12, absmax 0). Per-wave partials, no barriers.
__global__ __launch_bounds__(128, 6) void ssim_row_kernel(
    const float* __restrict__ pred, const float* __restrict__ targ,
    GaussHalf gh, float* __restrict__ partials)
{
    const int t = threadIdx.x;
    const int lane = t & 63;
    // wave-uniform row id, forced scalar so the SRDs are SGPR-resident
    const int wid = __builtin_amdgcn_readfirstlane((blockIdx.x << 1) | (t >> 6));

    const int l8 = 8 * lane;
    const int vL1 = 4 * (l8 - 5);    // tap -5  (OOB->0 at lane 0)
    const int vL4 = 4 * (l8 - 4);    // taps -4..-1
    const int vA  = 4 * l8;          // taps  0..3
    const int vB  = 4 * (l8 + 4);    // taps  4..7
    const int vR4 = 4 * (l8 + 8);    // taps  8..11 (OOB->0 at lane 63)
    const int vR1 = 4 * (l8 + 12);   // tap  12

    const u32x4_t sp = make_row_srsrc(pred + (long long)wid * 512);
    const u32x4_t sq = make_row_srsrc(targ + (long long)wid * 512);

    const float  pL1 = bl_x1(sp, vL1);
    const float4 pL4 = bl_x4(sp, vL4);
    const float4 pA  = bl_x4(sp, vA);
    const float4 pB  = bl_x4(sp, vB);
    const float4 pR4 = bl_x4(sp, vR4);
    const float  pR1 = bl_x1(sp, vR1);
    const float  qL1 = bl_x1(sq, vL1);
    const float4 qL4 = bl_x4(sq, vL4);
    const float4 qA  = bl_x4(sq, vA);
    const float4 qB  = bl_x4(sq, vB);
    const float4 qR4 = bl_x4(sq, vR4);
    const float  qR1 = bl_x1(sq, vR1);
    asm volatile("s_waitcnt vmcnt(0)" ::: "memory");
    __builtin_amdgcn_sched_barrier(0);

    const float pv[18] = {pL1, pL4.x, pL4.y, pL4.z, pL4.w,
                          pA.x, pA.y, pA.z, pA.w, pB.x, pB.y, pB.z, pB.w,
                          pR4.x, pR4.y, pR4.z, pR4.w, pR1};
    const float qv[18] = {qL1, qL4.x, qL4.y, qL4.z, qL4.w,
                          qA.x, qA.y, qA.z, qA.w, qB.x, qB.y, qB.z, qB.w,
                          qR4.x, qR4.y, qR4.z, qR4.w, qR1};

    const __half2 pm = __halves2half2(__float2half(1.f), __float2half(-1.f));
    const __half2 C11 = __builtin_bit_cast(__half2, gh.c11);
    const __half2 C22 = __builtin_bit_cast(__half2, gh.c22);

    // w[i] = (u,v) as half2 at row px (8*lane - 5 + i); s[i] = (u^2,v^2).
    // OOB-zero loads make the pad taps (0,0) with no masking.
    __half2 w[18], s[18];
    #pragma unroll
    for (int i = 0; i < 18; ++i) {
        w[i] = __floats2half2_rn(pv[i] + qv[i], pv[i] - qv[i]);
        s[i] = __hmul2(w[i], w[i]);
    }

    float acc = 0.f;
    #pragma unroll
    for (int px = 0; px < 8; ++px) {
        __half2 AB  = __builtin_bit_cast(__half2, 0u);
        __half2 SUV = __builtin_bit_cast(__half2, 0u);
        #pragma unroll
        for (int k = 0; k < WS; ++k) {
            AB  = __hfma2(__builtin_bit_cast(__half2, gh.gA[k]),
                          w[px + k], AB);
            SUV = __hfma2(__builtin_bit_cast(__half2, gh.gS[k]),
                          s[px + k], SUV);
        }
        const __half2 ab2  = __hmul2(AB, AB);                   // (A2,B2)
        const __half2 t2d2 = __hfma2(__lowhigh2highlow(ab2), pm, ab2);
        const __half2 tsds = __hfma2(__lowhigh2highlow(SUV), pm, SUV);
        const __half2 dn1  = __hfma2(t2d2, pm, C11);   // (den1, num1)
        const __half2 dl   = __hsub2(tsds, t2d2);      // (ts-t2, d2-ds)
        const __half2 dn2  = __hfma2(dl, pm, C22);     // (den2, num2)
        const __half2 nd   = __hmul2(dn1, dn2);        // (dd, nn)
        const float dd = __half2float(__low2half(nd));
        const float nn = __half2float(__high2half(nd));
        acc = fmaf(nn, __builtin_amdgcn_rcpf(dd), acc);
    }

    // wave shuffle reduction; lane 0 writes this wave's partial.
    #pragma unroll
    for (int offr = 32; offr > 0; offr >>= 1)
        acc += __shfl_down(acc, offr);
    if (lane == 0)
        partials[wid] = acc;
}

// Sum 24576 per-wave partials in double; the 10 zero-pad rows per (b,c)
// contribute ssim == 1 exactly: 16*3*10*512 = 245760 elements.
// Total elements: 16*3*522*512 = 12828672.
__global__ __launch_bounds__(1024) void ssim_final_kernel(
    const float* __restrict__ partials, float* __restrict__ out)
{
    const int t = threadIdx.x;
    double d = 0.0;
    #pragma unroll
    for (int i = 0; i < 24; ++i)
        d += (double)partials[t + 1024 * i];
    #pragma unroll
    for (int offr = 32; offr > 0; offr >>= 1)
        d += __shfl_down(d, offr);
    __shared__ double wsumd[16];
    const int lane = t & 63, wave = t >> 6;
    if (lane == 0) wsumd[wave] = d;
    __syncthreads();
    if (t == 0) {
        double s = 245760.0;
        #pragma unroll
        for (int i = 0; i < 16; ++i) s += wsumd[i];
        out[0] = (float)(1.0 - s / 12828672.0);
    }
}

static unsigned packh2(float x) {
    const __half h = __float2half(x);
    unsigned short hb;
    __builtin_memcpy(&hb, &h, 2);
    return ((unsigned)hb << 16) | hb;
}

extern "C" void kernel_launch(void* const* d_in, const int* in_sizes, int n_in,
                              void* d_out, int out_size, void* d_ws, size_t ws_size,
                              hipStream_t stream) {
    const float* pred = (const float*)d_in[0];
    const float* targ = (const float*)d_in[1];
    float* out = (float*)d_out;
    float* partials = (float*)d_ws;   // 24576 floats

    // Gaussian window exactly as the reference (sigma=1.5, ws=11),
    // prescaled: gA = g/sqrt(2) (linear chain), gS = g/2 (square chain),
    // duplicated into (h,h) half2 constants.
    GaussHalf gh;
    double graw[WS], s = 0.0;
    for (int i = 0; i < WS; ++i) {
        const double c = (double)(i - WS / 2);
        graw[i] = exp(-c * c / (2.0 * 1.5 * 1.5));
        s += graw[i];
    }
    for (int i = 0; i < WS; ++i) {
        const double g = graw[i] / s;
        gh.gA[i] = packh2((float)(g * 0.70710678118654752));
        gh.gS[i] = packh2((float)(g * 0.5));
    }
    gh.c11 = packh2(0.0001f);
    gh.c22 = packh2(0.0009f);

    ssim_row_kernel<<<12288, 128, 0, stream>>>(pred, targ, gh, partials);
    ssim_final_kernel<<<1, 1024, 0, stream>>>(partials, out);
}